// Round 1
// baseline (48.821 us; speedup 1.0000x reference)
//
#include <hip/hip_runtime.h>

// SphericalHarmonicsLighting
// B=16, V=262144 (2^18). Inputs: light(3) [UNUSED], normals(B,V,3) f32, sh_coeffs(27) f32.
// Output: E_rgb (B,V,3) f32.
//
// Faithful-to-torch view quirk: E[b,v,c] = sum_j Nown[j] * (M[c][row i] . Naug[b, base+j])
//   with i = v >> 16, base = (4*v) & (V-1), Nown/Naug = (nx,ny,nz,1).

#define SH_V 262144
#define SH_B 16

__global__ __launch_bounds__(256) void sh_lighting_kernel(
    const float* __restrict__ normals,   // [B, V, 3]
    const float* __restrict__ sh,        // [27]
    float* __restrict__ out)             // [B, V, 3]
{
    const int t   = blockIdx.x * blockDim.x + threadIdx.x;  // 0 .. B*V/4-1 (2^20)
    const int b   = t >> 16;        // / (V/4)
    const int rem = t & 65535;      // vertex-group index within batch
    const int v0  = rem << 2;       // first of 4 consecutive vertices
    const int i   = rem >> 14;      // M row index (0..3), wave-uniform
    const int nb  = (rem & 16383) << 4;  // neighbor base vertex = (4*v0) & (V-1)

    // ---- build row i of M[c] for each RGB channel (Ramamoorthi & Hanrahan) ----
    const float c0 = 0.429043f, c1 = 0.511664f, c2 = 0.743125f,
                c3 = 0.886227f, c4 = 0.247708f;
    float Mr[3][4];
#pragma unroll
    for (int c = 0; c < 3; ++c) {
        const float L0 = sh[9*c+0], L1 = sh[9*c+1], L2 = sh[9*c+2];
        const float L3 = sh[9*c+3], L4 = sh[9*c+4], L5 = sh[9*c+5];
        const float L6 = sh[9*c+6], L7 = sh[9*c+7], L8 = sh[9*c+8];
        if (i == 0) {
            Mr[c][0] = c0*L8;  Mr[c][1] = c0*L4;  Mr[c][2] = c0*L7;  Mr[c][3] = c1*L3;
        } else if (i == 1) {
            Mr[c][0] = c0*L4;  Mr[c][1] = -c0*L8; Mr[c][2] = c0*L5;  Mr[c][3] = c1*L1;
        } else if (i == 2) {
            Mr[c][0] = c0*L7;  Mr[c][1] = c0*L5;  Mr[c][2] = c2*L6;  Mr[c][3] = c1*L2;
        } else {
            Mr[c][0] = c1*L3;  Mr[c][1] = c1*L1;  Mr[c][2] = c1*L2;  Mr[c][3] = c3*L0 - c4*L6;
        }
    }

    const float* nbase = normals + (size_t)b * (SH_V * 3);

    // ---- neighbor normals: 16 vertices starting at nb -> 48 floats = 12 x float4 ----
    float ngf[48];
    {
        const float4* p4 = (const float4*)(nbase + (size_t)nb * 3);  // 192B-aligned offset
#pragma unroll
        for (int k = 0; k < 12; ++k) {
            float4 q = p4[k];
            ngf[4*k+0] = q.x; ngf[4*k+1] = q.y; ngf[4*k+2] = q.z; ngf[4*k+3] = q.w;
        }
    }

    // ---- own normals: 4 vertices starting at v0 -> 12 floats = 3 x float4 ----
    float owf[12];
    {
        const float4* p4 = (const float4*)(nbase + (size_t)v0 * 3);  // 48B-aligned offset
#pragma unroll
        for (int k = 0; k < 3; ++k) {
            float4 q = p4[k];
            owf[4*k+0] = q.x; owf[4*k+1] = q.y; owf[4*k+2] = q.z; owf[4*k+3] = q.w;
        }
    }

    // ---- compute 4 vertices x 3 channels ----
    float res[12];
#pragma unroll
    for (int jj = 0; jj < 4; ++jj) {
        const float nx = owf[3*jj+0], ny = owf[3*jj+1], nz = owf[3*jj+2];
#pragma unroll
        for (int c = 0; c < 3; ++c) {
            float e = 0.0f;
#pragma unroll
            for (int j = 0; j < 4; ++j) {
                const int nv = 4*jj + j;  // neighbor slot within our 16-vertex block
                const float s = Mr[c][3]
                              + Mr[c][0] * ngf[nv*3+0]
                              + Mr[c][1] * ngf[nv*3+1]
                              + Mr[c][2] * ngf[nv*3+2];
                const float w = (j == 0) ? nx : (j == 1) ? ny : (j == 2) ? nz : 1.0f;
                e += w * s;
            }
            res[3*jj + c] = e;
        }
    }

    // ---- store 12 floats = 3 x float4 ----
    float4* o4 = (float4*)(out + (size_t)b * (SH_V * 3) + (size_t)v0 * 3);
#pragma unroll
    for (int k = 0; k < 3; ++k) {
        o4[k] = make_float4(res[4*k+0], res[4*k+1], res[4*k+2], res[4*k+3]);
    }
}

extern "C" void kernel_launch(void* const* d_in, const int* in_sizes, int n_in,
                              void* d_out, int out_size, void* d_ws, size_t ws_size,
                              hipStream_t stream) {
    // d_in[0] = light (3) -- unused by the reference computation
    const float* normals = (const float*)d_in[1];   // B*V*3
    const float* sh      = (const float*)d_in[2];   // 27
    float* out           = (float*)d_out;           // B*V*3

    const int total_threads = SH_B * (SH_V / 4);    // 2^20
    const int block = 256;
    const int grid  = total_threads / block;        // 4096
    sh_lighting_kernel<<<grid, block, 0, stream>>>(normals, sh, out);
}

// Round 2
// 26.560 us; speedup vs baseline: 1.8381x; 1.8381x over previous
//
#include <hip/hip_runtime.h>

// SphericalHarmonicsLighting — B=16, V=262144 (2^18)
// E[b,v,c] = sum_j Nown[j] * (M[c][row i] . Naug[b, (4v mod V)+j]),
//   i = v>>16 (block-uniform), Nown/Naug = (nx,ny,nz,1)  [torch .view() quirk]
//
// Structure: block = 256 threads handles 1024 consecutive vertices.
//  Phase 1: stage the 4096-vertex neighbor window (48KB, contiguous) into LDS
//           via global_load_lds (fully coalesced, 12 x 16B/lane).
//  Phase 2: thread tid computes vertices u = k*256+tid: own normal via dense
//           float3 global load (12B lane stride, contiguous/wave), neighbors via
//           3x ds_read_b128 at 48B lane stride (conflict-free: 12-dword stride
//           covers all 32 banks, 8 lanes/bank = b128 minimum), dense float3 store.

#define SH_V 262144
#define SH_B 16
#define BLK_VERTS 1024
#define NBR_FLOATS (BLK_VERTS * 4 * 3)   // 12288 floats = 48 KiB

__global__ __launch_bounds__(256) void sh_lighting_kernel(
    const float* __restrict__ normals,   // [B, V, 3]
    const float* __restrict__ sh,        // [27]
    float* __restrict__ out)             // [B, V, 3]
{
    __shared__ float nbr[NBR_FLOATS];

    const int tid = threadIdx.x;
    const int blk = blockIdx.x;
    const int b   = blk >> 8;            // 256 blocks per batch image
    const int rem = blk & 255;
    const int v0  = rem << 10;           // first vertex of this block (batch-local)
    const int i   = rem >> 6;            // M row index 0..3 (block-uniform)
    const int nb0 = (rem & 63) << 12;    // neighbor window base vertex = (4*v0) mod V

    const float* nbase = normals + (size_t)b * (SH_V * 3);

    // ---- Phase 1: coalesced global -> LDS staging of neighbor window ----
    {
        const float* src = nbase + (size_t)nb0 * 3;   // 12288 floats, 16B-aligned
#pragma unroll
        for (int k = 0; k < 12; ++k) {
            const int idx = k * 256 + tid;            // float4 index 0..3071
            __builtin_amdgcn_global_load_lds(
                (const __attribute__((address_space(1))) void*)(src + (size_t)idx * 4),
                (__attribute__((address_space(3))) void*)(&nbr[idx * 4]),
                16, 0, 0);
        }
    }

    // ---- M row i for each RGB channel (scalar: i is block-uniform) ----
    const float c0 = 0.429043f, c1 = 0.511664f, c2 = 0.743125f,
                c3 = 0.886227f, c4 = 0.247708f;
    float Mr[3][4];
#pragma unroll
    for (int c = 0; c < 3; ++c) {
        const float L0 = sh[9*c+0], L1 = sh[9*c+1], L2 = sh[9*c+2];
        const float L3 = sh[9*c+3], L4 = sh[9*c+4], L5 = sh[9*c+5];
        const float L6 = sh[9*c+6], L7 = sh[9*c+7], L8 = sh[9*c+8];
        if (i == 0) {
            Mr[c][0] = c0*L8;  Mr[c][1] = c0*L4;  Mr[c][2] = c0*L7;  Mr[c][3] = c1*L3;
        } else if (i == 1) {
            Mr[c][0] = c0*L4;  Mr[c][1] = -c0*L8; Mr[c][2] = c0*L5;  Mr[c][3] = c1*L1;
        } else if (i == 2) {
            Mr[c][0] = c0*L7;  Mr[c][1] = c0*L5;  Mr[c][2] = c2*L6;  Mr[c][3] = c1*L2;
        } else {
            Mr[c][0] = c1*L3;  Mr[c][1] = c1*L1;  Mr[c][2] = c1*L2;  Mr[c][3] = c3*L0 - c4*L6;
        }
    }

    __syncthreads();   // drains global_load_lds (compiler emits vmcnt(0))

    float* obase = out + (size_t)b * (SH_V * 3);

    // ---- Phase 2: compute 4 vertices per thread, all accesses dense ----
#pragma unroll
    for (int k = 0; k < 4; ++k) {
        const int u = k * 256 + tid;         // local vertex 0..1023
        const int v = v0 + u;                // batch-local vertex

        // own normal: 12B at 12B lane stride -> contiguous 768B per wave
        const float3 own = *(const float3*)(nbase + (size_t)v * 3);

        // neighbors: LDS floats [12u, 12u+12) = 4 vertices x 3 comps
        const float4* lp = (const float4*)(&nbr[12 * u]);   // 48B lane stride
        const float4 q0 = lp[0], q1 = lp[1], q2 = lp[2];
        const float ng[12] = {q0.x,q0.y,q0.z,q0.w, q1.x,q1.y,q1.z,q1.w, q2.x,q2.y,q2.z,q2.w};

        // factored form: e_c = Mr[c] . (dx,dy,dz,dw)
        const float dx = fmaf(own.x, ng[0], fmaf(own.y, ng[3], fmaf(own.z, ng[6], ng[9])));
        const float dy = fmaf(own.x, ng[1], fmaf(own.y, ng[4], fmaf(own.z, ng[7], ng[10])));
        const float dz = fmaf(own.x, ng[2], fmaf(own.y, ng[5], fmaf(own.z, ng[8], ng[11])));
        const float dw = own.x + own.y + own.z + 1.0f;

        float3 ev;
        ev.x = fmaf(Mr[0][0], dx, fmaf(Mr[0][1], dy, fmaf(Mr[0][2], dz, Mr[0][3] * dw)));
        ev.y = fmaf(Mr[1][0], dx, fmaf(Mr[1][1], dy, fmaf(Mr[1][2], dz, Mr[1][3] * dw)));
        ev.z = fmaf(Mr[2][0], dx, fmaf(Mr[2][1], dy, fmaf(Mr[2][2], dz, Mr[2][3] * dw)));

        // store: 12B at 12B lane stride -> contiguous 768B per wave
        *(float3*)(obase + (size_t)v * 3) = ev;
    }
}

extern "C" void kernel_launch(void* const* d_in, const int* in_sizes, int n_in,
                              void* d_out, int out_size, void* d_ws, size_t ws_size,
                              hipStream_t stream) {
    // d_in[0] = light (3) -- unused by the reference computation
    const float* normals = (const float*)d_in[1];   // B*V*3
    const float* sh      = (const float*)d_in[2];   // 27
    float* out           = (float*)d_out;           // B*V*3

    const int grid = SH_B * (SH_V / BLK_VERTS);     // 16 * 256 = 4096 blocks
    sh_lighting_kernel<<<grid, 256, 0, stream>>>(normals, sh, out);
}